// Round 1
// baseline (401.379 us; speedup 1.0000x reference)
//
#include <hip/hip_runtime.h>

// 1-D multi-resolution linear interp, 6 levels (sizes 8..256, 8 channels),
// N=2M query points, output (N, 48) f32.  HBM-write-bound: ~384 MB out.
//
// Layout strategy:
//  - all volumes packed in LDS: level l starts at row (8<<l)-8, 504 rows total
//  - block tile = 256 rows; one thread = one output float4 (12 per row),
//    k-loop over 12 gives fully coalesced dwordx4 stores.

constexpr int NLEV = 6;
constexpr int CCH = 8;                     // channels
constexpr int ROWS_TOTAL = 504;            // 8+16+32+64+128+256
constexpr int TILE = 256;                  // rows per block == blockDim.x
constexpr int F4_PER_ROW = 12;             // 48 floats / 4
constexpr int F4_PER_TILE = TILE * F4_PER_ROW;

__global__ __launch_bounds__(TILE) void interp_multires_kernel(
    const float* __restrict__ t,
    const float* __restrict__ v0, const float* __restrict__ v1,
    const float* __restrict__ v2, const float* __restrict__ v3,
    const float* __restrict__ v4, const float* __restrict__ v5,
    float* __restrict__ out, int n)
{
    __shared__ __align__(16) float vol_lds[ROWS_TOTAL * CCH];  // 16128 B
    __shared__ float t_lds[TILE];

    const int tid = threadIdx.x;

    // ---- stage volumes into LDS (float4 loads; all sizes divisible by 4) ----
    const float* vps[NLEV] = {v0, v1, v2, v3, v4, v5};
#pragma unroll
    for (int l = 0; l < NLEV; ++l) {
        const int sz = 8 << l;                    // rows at this level
        const int offf = (sz - 8) * CCH;          // float offset of level start
        const int n4 = sz * CCH / 4;              // float4 count
        float4* dst = (float4*)(vol_lds + offf);
        const float4* src = (const float4*)vps[l];
        for (int i = tid; i < n4; i += TILE) dst[i] = src[i];
    }

    // ---- stage clamped t for this block's 256 rows ----
    {
        const int grow = blockIdx.x * TILE + tid;
        float tv = (grow < n) ? t[grow] : 0.0f;
        t_lds[tid] = fminf(fmaxf(tv, 0.0f), 1.0f);
    }
    __syncthreads();

    const long long base4 = (long long)blockIdx.x * F4_PER_TILE;
    float4* out4 = (float4*)out;
    const int row_base = blockIdx.x * TILE;

#pragma unroll
    for (int k = 0; k < F4_PER_ROW; ++k) {
        const int idx = k * TILE + tid;           // 0..3071, lane-consecutive
        const int row = idx / F4_PER_ROW;         // magic-mul div by 12
        const int q   = idx - row * F4_PER_ROW;   // 0..11
        if (row_base + row < n) {
            const int lvl = q >> 1;
            const int cb  = (q & 1) * 4;          // channel base 0 or 4
            const int size = 8 << lvl;

            const float tc  = t_lds[row];
            const float pos = tc * (float)(size - 1);
            int i0 = (int)floorf(pos);
            i0 = min(max(i0, 0), size - 2);
            const float w  = pos - (float)i0;
            const float om = 1.0f - w;

            // level offset rows == size-8; row i0, channels [cb..cb+3]
            const float* p = vol_lds + ((size - 8) + i0) * CCH + cb;
            const float4 a = *(const float4*)p;
            const float4 b = *(const float4*)(p + CCH);

            float4 r;
            r.x = a.x * om + b.x * w;
            r.y = a.y * om + b.y * w;
            r.z = a.z * om + b.z * w;
            r.w = a.w * om + b.w * w;
            out4[base4 + idx] = r;
        }
    }
}

extern "C" void kernel_launch(void* const* d_in, const int* in_sizes, int n_in,
                              void* d_out, int out_size, void* d_ws, size_t ws_size,
                              hipStream_t stream) {
    const float* t  = (const float*)d_in[0];
    const float* v0 = (const float*)d_in[1];
    const float* v1 = (const float*)d_in[2];
    const float* v2 = (const float*)d_in[3];
    const float* v3 = (const float*)d_in[4];
    const float* v4 = (const float*)d_in[5];
    const float* v5 = (const float*)d_in[6];
    float* out = (float*)d_out;

    const int n = in_sizes[0];                 // t is (N,1) -> N elements
    const int grid = (n + TILE - 1) / TILE;
    interp_multires_kernel<<<grid, TILE, 0, stream>>>(t, v0, v1, v2, v3, v4, v5,
                                                      out, n);
}

// Round 3
// 401.179 us; speedup vs baseline: 1.0005x; 1.0005x over previous
//
#include <hip/hip_runtime.h>

// 1-D multi-resolution linear interp, 6 levels (sizes 8..256, 8 channels),
// N=2M points -> (N, 48) f32.  Write-bound: ~384 MB out, ~8 MB t in.
//
// R3 = R2 with ext_vector_type(4) for the nontemporal store (HIP float4 is a
// struct; the builtin needs a real vector type):
//  - 4096 persistent-ish blocks, grid-stride over output float4 indices
//  - volumes packed once per block into LDS, single __syncthreads
//  - t direct from global (12-way reuse via L1)
//  - non-temporal dwordx4 stores (output never re-read)

typedef float fx4 __attribute__((ext_vector_type(4)));

constexpr int NLEV = 6;
constexpr int CCH = 8;                      // channels
constexpr int ROWS_TOTAL = 504;             // 8+16+32+64+128+256
constexpr int BLK = 256;
constexpr int F4_PER_ROW = 12;              // 48 floats / 4

__global__ __launch_bounds__(BLK) void interp_multires_kernel(
    const float* __restrict__ t,
    const float* __restrict__ v0, const float* __restrict__ v1,
    const float* __restrict__ v2, const float* __restrict__ v3,
    const float* __restrict__ v4, const float* __restrict__ v5,
    float* __restrict__ out, int n)
{
    __shared__ __align__(16) float vol_lds[ROWS_TOTAL * CCH];  // 16128 B

    const int tid = threadIdx.x;

    // ---- stage all volumes into LDS once per block ----
    const float* vps[NLEV] = {v0, v1, v2, v3, v4, v5};
#pragma unroll
    for (int l = 0; l < NLEV; ++l) {
        const int sz = 8 << l;
        const int offf = (sz - 8) * CCH;
        const int n4 = sz * CCH / 4;
        fx4* dst = (fx4*)(vol_lds + offf);
        const fx4* src = (const fx4*)vps[l];
        for (int i = tid; i < n4; i += BLK) dst[i] = src[i];
    }
    __syncthreads();

    const int total4 = n * F4_PER_ROW;       // 24M, fits int32
    const int stride = gridDim.x * BLK;
    fx4* __restrict__ out4 = (fx4*)out;

    for (int g = blockIdx.x * BLK + tid; g < total4; g += stride) {
        const int row = g / F4_PER_ROW;       // magic-mul div
        const int q   = g - row * F4_PER_ROW; // 0..11
        const int lvl = q >> 1;
        const int cb  = (q & 1) * 4;          // channel base 0 or 4
        const int size = 8 << lvl;

        const float tc  = fminf(fmaxf(t[row], 0.0f), 1.0f);
        const float pos = tc * (float)(size - 1);
        int i0 = (int)floorf(pos);
        i0 = min(max(i0, 0), size - 2);
        const float w  = pos - (float)i0;
        const float om = 1.0f - w;

        const float* p = vol_lds + ((size - 8) + i0) * CCH + cb;
        const fx4 a = *(const fx4*)p;
        const fx4 b = *(const fx4*)(p + CCH);

        const fx4 r = a * om + b * w;
        __builtin_nontemporal_store(r, out4 + g);
    }
}

extern "C" void kernel_launch(void* const* d_in, const int* in_sizes, int n_in,
                              void* d_out, int out_size, void* d_ws, size_t ws_size,
                              hipStream_t stream) {
    const float* t  = (const float*)d_in[0];
    const float* v0 = (const float*)d_in[1];
    const float* v1 = (const float*)d_in[2];
    const float* v2 = (const float*)d_in[3];
    const float* v3 = (const float*)d_in[4];
    const float* v4 = (const float*)d_in[5];
    const float* v5 = (const float*)d_in[6];
    float* out = (float*)d_out;

    const int n = in_sizes[0];                    // N (t is (N,1))
    const int total4 = n * F4_PER_ROW;
    int grid = 4096;                              // persistent-ish, ~23 iters/thread
    const int max_grid = (total4 + BLK - 1) / BLK;
    if (grid > max_grid) grid = max_grid;
    interp_multires_kernel<<<grid, BLK, 0, stream>>>(t, v0, v1, v2, v3, v4, v5,
                                                     out, n);
}